// Round 8
// baseline (509.857 us; speedup 1.0000x reference)
//
#include <hip/hip_runtime.h>
#include <hip/hip_bf16.h>
#include <float.h>

#define NS 32768
#define KER 256
#define TOUT 32513
#define NATOM 256
#define NSTEP 16
#define BATCH 8
#define NBLK 255
#define XSTR 33024   // NS + 256 pad (zero-filled)
#define SW4(i) ((i) + (((i) >> 5) << 2))

typedef __attribute__((ext_vector_type(8))) _Float16 half8;
typedef __attribute__((ext_vector_type(16))) float f32x16;
typedef __attribute__((ext_vector_type(4))) unsigned int uint4v;

__device__ __forceinline__ void cmax(float& ba, float& bs, float& bi,
                                     float oa, float os, float oi) {
    if (oa > ba || (oa == ba && oi < bi)) { ba = oa; bs = os; bi = oi; }
}

__device__ __forceinline__ void fma8(float acc[8], float4 dA, float4 dB,
                                     float4 w0, float4 w1, float4 w2, float4 w3) {
    float w[16] = {w0.x,w0.y,w0.z,w0.w, w1.x,w1.y,w1.z,w1.w,
                   w2.x,w2.y,w2.z,w2.w, w3.x,w3.y,w3.z,w3.w};
    float dv[8] = {dA.x,dA.y,dA.z,dA.w, dB.x,dB.y,dB.z,dB.w};
#pragma unroll
    for (int i = 0; i < 8; ++i)
#pragma unroll
        for (int j = 0; j < 8; ++j)
            acc[j] = fmaf(dv[i], w[i + j], acc[j]);
}

__device__ __forceinline__ unsigned short f16hi(float v) {
    return __builtin_bit_cast(unsigned short, (_Float16)v);
}
__device__ __forceinline__ unsigned short f16lo(float v) {
    const _Float16 h = (_Float16)v;
    return __builtin_bit_cast(unsigned short, (_Float16)(v - (float)h));
}

// xhl4[i] = {hi01, hi23, lo01, lo23} f16 of x[i..i+3] (redundant quads, one
// b128 read covers hi+lo of 4 elems). dhF/dlF fragment-major as r7.
__global__ __launch_bounds__(256) void k_prep(const float* __restrict__ x,
                                              const float* __restrict__ d,
                                              uint4* __restrict__ xhl4,
                                              uint4* __restrict__ dhF,
                                              uint4* __restrict__ dlF) {
    const int gid = blockIdx.x * 256 + threadIdx.x;
    const int NXE = BATCH * XSTR;
    if (gid < NXE) {
        const int b = gid / XSTR, i = gid - b * XSTR;
        float v[4];
#pragma unroll
        for (int u = 0; u < 4; ++u)
            v[u] = (i + u < NS) ? x[b * NS + i + u] : 0.f;
        uint4 q;
        q.x = (unsigned int)f16hi(v[0]) | ((unsigned int)f16hi(v[1]) << 16);
        q.y = (unsigned int)f16hi(v[2]) | ((unsigned int)f16hi(v[3]) << 16);
        q.z = (unsigned int)f16lo(v[0]) | ((unsigned int)f16lo(v[1]) << 16);
        q.w = (unsigned int)f16lo(v[2]) | ((unsigned int)f16lo(v[3]) << 16);
        xhl4[gid] = q;
    } else {
        const int j = gid - NXE;
        if (j < NATOM * 32) {
            const int kg = j >> 8, atom = j & 255;
            const float* dp = d + atom * 256 + (kg << 3);
            uint4 hw, lw;
            hw.x = (unsigned int)f16hi(dp[0]) | ((unsigned int)f16hi(dp[1]) << 16);
            hw.y = (unsigned int)f16hi(dp[2]) | ((unsigned int)f16hi(dp[3]) << 16);
            hw.z = (unsigned int)f16hi(dp[4]) | ((unsigned int)f16hi(dp[5]) << 16);
            hw.w = (unsigned int)f16hi(dp[6]) | ((unsigned int)f16hi(dp[7]) << 16);
            lw.x = (unsigned int)f16lo(dp[0]) | ((unsigned int)f16lo(dp[1]) << 16);
            lw.y = (unsigned int)f16lo(dp[2]) | ((unsigned int)f16lo(dp[3]) << 16);
            lw.z = (unsigned int)f16lo(dp[4]) | ((unsigned int)f16lo(dp[5]) << 16);
            lw.w = (unsigned int)f16lo(dp[6]) | ((unsigned int)f16lo(dp[7]) << 16);
            dhF[(kg << 8) + atom] = hw;
            dlF[(kg << 8) + atom] = lw;
        }
    }
}

// 32x32x16_f16 MFMA correlation, 2m x 4n register tile.
// grid (64 t-chunks of 512, 4 atom-groups of 64, 8 b), block 256 (4 waves).
// Wave w: 64 atoms x 128 t = one bm 128-block (blk = 4c + w).
__global__ __launch_bounds__(256) void k_init(const uint4* __restrict__ xhl4,
                                              const uint4* __restrict__ dhF,
                                              const uint4* __restrict__ dlF,
                                              float2* __restrict__ bm) {
    const int c = blockIdx.x, mg = blockIdx.y, b = blockIdx.z;
    const int tid = threadIdx.x;
    const int w = tid >> 6, l = tid & 63;
    const int n = l & 31, h = l >> 5;
    __shared__ uint4 xw[768];   // 512-t window + 255 tail, packed quads
    const int t0 = c << 9;
    for (int i = tid; i < 768; i += 256)
        xw[i] = xhl4[b * XSTR + t0 + i];
    __syncthreads();

    f32x16 acc[2][4];
#pragma unroll
    for (int mt = 0; mt < 2; ++mt)
#pragma unroll
        for (int nt = 0; nt < 4; ++nt)
#pragma unroll
            for (int j = 0; j < 16; ++j) acc[mt][nt][j] = 0.f;

    const int abase = (mg << 6) + n;
    const int sbb = (w << 7) + n + (h << 3);
#pragma unroll 2
    for (int kk = 0; kk < 16; ++kk) {
        const int kg = (kk << 1) + h;
        const half8 ah0 = __builtin_bit_cast(half8, dhF[(kg << 8) + abase]);
        const half8 al0 = __builtin_bit_cast(half8, dlF[(kg << 8) + abase]);
        const half8 ah1 = __builtin_bit_cast(half8, dhF[(kg << 8) + abase + 32]);
        const half8 al1 = __builtin_bit_cast(half8, dlF[(kg << 8) + abase + 32]);
#pragma unroll
        for (int nt = 0; nt < 4; ++nt) {
            const int s0 = sbb + (nt << 5) + (kk << 4);
            const uint4 q0 = xw[s0], q1 = xw[s0 + 4];
            const uint4v hv = {q0.x, q0.y, q1.x, q1.y};
            const uint4v lv = {q0.z, q0.w, q1.z, q1.w};
            const half8 bh = __builtin_bit_cast(half8, hv);
            const half8 bl = __builtin_bit_cast(half8, lv);
            acc[0][nt] = __builtin_amdgcn_mfma_f32_32x32x16_f16(ah0, bl, acc[0][nt], 0, 0, 0);
            acc[0][nt] = __builtin_amdgcn_mfma_f32_32x32x16_f16(al0, bh, acc[0][nt], 0, 0, 0);
            acc[0][nt] = __builtin_amdgcn_mfma_f32_32x32x16_f16(ah0, bh, acc[0][nt], 0, 0, 0);
            acc[1][nt] = __builtin_amdgcn_mfma_f32_32x32x16_f16(ah1, bl, acc[1][nt], 0, 0, 0);
            acc[1][nt] = __builtin_amdgcn_mfma_f32_32x32x16_f16(al1, bh, acc[1][nt], 0, 0, 0);
            acc[1][nt] = __builtin_amdgcn_mfma_f32_32x32x16_f16(ah1, bh, acc[1][nt], 0, 0, 0);
        }
    }

    // Epilogue: C col=lane&31 (t within n-tile), row=(r&3)+8*(r>>2)+4*h (atom).
    // Wave w owns bm block blk = 4c + w for all 64 atoms.
    const int blk = (c << 2) + w;
    if (blk < NBLK) {
#pragma unroll
        for (int mt = 0; mt < 2; ++mt) {
#pragma unroll
            for (int r = 0; r < 16; ++r) {
                const int atom = (mg << 6) + (mt << 5) + (r & 3) + (((r >> 2)) << 3) + (h << 2);
                const float fa = (float)(atom * TOUT);
                float ba = -1.f, bsg = 0.f, bi = 3.0e7f;
#pragma unroll
                for (int nt = 0; nt < 4; ++nt) {
                    const int t = t0 + (w << 7) + (nt << 5) + n;
                    const float v = acc[mt][nt][r];
                    const float av = fabsf(v);
                    if (t < TOUT && av > ba) { ba = av; bsg = v; bi = fa + (float)t; }
                }
#pragma unroll
                for (int m = 1; m <= 16; m <<= 1) {
                    const float oa = __shfl_xor(ba, m, 32);
                    const float os = __shfl_xor(bsg, m, 32);
                    const float oi = __shfl_xor(bi, m, 32);
                    cmax(ba, bsg, bi, oa, os, oi);
                }
                if (n == 0)
                    bm[(size_t)((b << 8) + atom) * NBLK + blk] = make_float2(bsg, bi);
            }
        }
    }
}

// Per-atom (level-2) maxima over all blocks -> l2 buffer 0.
__global__ __launch_bounds__(256) void k_lvl2(const float2* __restrict__ bm,
                                              float4* __restrict__ l2) {
    const int b = blockIdx.y;
    const int oglob = blockIdx.x * 8 + (threadIdx.x >> 5);
    const int lane = threadIdx.x & 31;
    const float2* row = bm + (size_t)(b * NATOM + oglob) * NBLK;
    float ba = -1.f, bsg = 0.f, bi = 3.0e7f;
    for (int i = lane; i < NBLK; i += 32) {
        const float2 e = row[i];
        cmax(ba, bsg, bi, fabsf(e.x), e.x, e.y);
    }
#pragma unroll
    for (int m = 16; m >= 1; m >>= 1) {
        const float oa = __shfl_xor(ba, m, 32);
        const float os = __shfl_xor(bsg, m, 32);
        const float oi = __shfl_xor(bi, m, 32);
        cmax(ba, bsg, bi, oa, os, oi);
    }
    if (lane == 0) l2[(b << 8) + oglob] = make_float4(ba, bsg, bi, 0.f);
}

// One MP step with persistent double-buffered residual (unchanged from r7).
__global__ __launch_bounds__(512) void k_step(const float* __restrict__ d,
                                              const float* __restrict__ resid_src,
                                              float* __restrict__ resid_dst,
                                              float2* __restrict__ bm,
                                              float4* __restrict__ l2,
                                              int* __restrict__ pos_a,
                                              int* __restrict__ atom_a,
                                              float* __restrict__ amp_a,
                                              int step) {
    const int og = blockIdx.x, b = blockIdx.y;
    const int tid = threadIdx.x;
    const int wave = tid >> 6, lane = tid & 63;
    __shared__ float dt[2048];
    __shared__ float rsu[1024];
    __shared__ float4 sred[8];
    __shared__ float4 upd[8][5];
    __shared__ int sh_pos, sh_atom;
    __shared__ float sh_amp;

    ((float4*)dt)[tid] = ((const float4*)(d + og * 2048))[tid];
    const float4* l2r = l2 + (step & 1) * (BATCH * NATOM);
    float4*       l2w = l2 + ((step + 1) & 1) * (BATCH * NATOM);

    {
        float ba = -1.f, bsg = 0.f, bi = 3.0e7f;
        if (tid < 256) {
            const float4 e = l2r[(b << 8) + tid];
            ba = e.x; bsg = e.y; bi = e.z;
        }
#pragma unroll
        for (int m = 32; m >= 1; m >>= 1) {
            const float oa = __shfl_xor(ba, m);
            const float os = __shfl_xor(bsg, m);
            const float oi = __shfl_xor(bi, m);
            cmax(ba, bsg, bi, oa, os, oi);
        }
        if (lane == 0) sred[wave] = make_float4(ba, bsg, bi, 0.f);
    }
    __syncthreads();
    if (tid == 0) {
        float4 r = sred[0];
#pragma unroll
        for (int i = 1; i < 8; ++i) {
            const float4 q = sred[i];
            if (q.x > r.x || (q.x == r.x && q.z < r.z)) r = q;
        }
        const int idx = (int)r.z;
        const int atom = idx / TOUT;
        const int pos = idx - atom * TOUT;
        sh_pos = pos; sh_atom = atom; sh_amp = r.y;
        if (og == 0) {
            pos_a[step * BATCH + b] = pos;
            atom_a[step * BATCH + b] = atom;
            amp_a[step * BATCH + b] = r.y;
        }
    }
    __syncthreads();
    const int p = sh_pos, atom_s = sh_atom;
    const float amp = sh_amp;

    for (int i = tid; i < 1024; i += 512) {
        const int g = (og << 10) + i;
        float v = resid_src[(size_t)b * NS + g];
        const int off = g - p;
        if (off >= 0 && off < KER)
            v = __fsub_rn(v, __fmul_rn(amp, d[atom_s * KER + off]));
        resid_dst[(size_t)b * NS + g] = v;
    }

    int tlo = p - 255; if (tlo < 0) tlo = 0;
    int thi = p + 255; if (thi > TOUT - 1) thi = TOUT - 1;
    const int bs0 = tlo >> 7, be0 = thi >> 7;
    const int rbase = bs0 << 7;
    const int nblks = be0 - bs0 + 1;
    const int rlen = (nblks << 7) + 255;
    for (int i = tid; i < rlen; i += 512) {
        const int g = rbase + i;
        float v = (g < NS) ? resid_src[(size_t)b * NS + g] : 0.f;
        const int off = g - p;
        if (g < NS && off >= 0 && off < KER)
            v = __fsub_rn(v, __fmul_rn(amp, d[atom_s * KER + off]));
        rsu[SW4(i)] = v;
    }
    __syncthreads();

    const int lg = lane >> 4, l16 = lane & 15;
    const float* dp = dt + (wave << 8) + (lg << 6);
    const int atomg = (og << 3) + wave;
    for (int bb = 0; bb < nblks; ++bb) {
        const int blk = bs0 + bb;
        const int t0r = (bb << 7) + (l16 << 3) + (lg << 6);
        float acc[8];
#pragma unroll
        for (int j = 0; j < 8; ++j) acc[j] = 0.f;
        float4 A0 = *(const float4*)(rsu + SW4(t0r));
        float4 A1 = *(const float4*)(rsu + SW4(t0r + 4));
        float4 B0 = *(const float4*)(rsu + SW4(t0r + 8));
        float4 B1 = *(const float4*)(rsu + SW4(t0r + 12));
#pragma unroll
        for (int kk = 0; kk < 64; kk += 16) {
            const float4 d0 = *(const float4*)(dp + kk);
            const float4 d1 = *(const float4*)(dp + kk + 4);
            const float4 N0 = *(const float4*)(rsu + SW4(t0r + kk + 16));
            const float4 N1 = *(const float4*)(rsu + SW4(t0r + kk + 20));
            fma8(acc, d0, d1, A0, A1, B0, B1);
            const float4 d2 = *(const float4*)(dp + kk + 8);
            const float4 d3 = *(const float4*)(dp + kk + 12);
            const float4 M0 = *(const float4*)(rsu + SW4(t0r + kk + 24));
            const float4 M1 = *(const float4*)(rsu + SW4(t0r + kk + 28));
            fma8(acc, d2, d3, B0, B1, N0, N1);
            A0 = N0; A1 = N1; B0 = M0; B1 = M1;
        }
#pragma unroll
        for (int j = 0; j < 8; ++j) {
            acc[j] += __shfl_xor(acc[j], 16);
            acc[j] += __shfl_xor(acc[j], 32);
        }
        float ba = -1.f, bsg = 0.f, bi = 3.0e7f;
        const int tbp = rbase + (bb << 7) + (l16 << 3);
#pragma unroll
        for (int j = 0; j < 8; ++j) {
            const int t = tbp + j;
            const float av = fabsf(acc[j]);
            if (t < TOUT && av > ba) { ba = av; bsg = acc[j]; bi = (float)(atomg * TOUT + t); }
        }
#pragma unroll
        for (int m = 32; m >= 1; m >>= 1) {
            const float oa = __shfl_xor(ba, m);
            const float os = __shfl_xor(bsg, m);
            const float oi = __shfl_xor(bi, m);
            cmax(ba, bsg, bi, oa, os, oi);
        }
        if (lane == 0) {
            bm[(size_t)(b * NATOM + atomg) * NBLK + blk] = make_float2(bsg, bi);
            upd[wave][bb] = make_float4(ba, bsg, bi, 0.f);
        }
    }
    __syncthreads();

    {
        float ba = -1.f, bsg = 0.f, bi = 3.0e7f;
        const float2* row = bm + (size_t)(b * NATOM + atomg) * NBLK;
        for (int i = lane; i < NBLK; i += 64) {
            if (i >= bs0 && i <= be0) {
                const float4 e2 = upd[wave][i - bs0];
                cmax(ba, bsg, bi, e2.x, e2.y, e2.z);
            } else {
                const float2 e2 = row[i];
                cmax(ba, bsg, bi, fabsf(e2.x), e2.x, e2.y);
            }
        }
#pragma unroll
        for (int m = 32; m >= 1; m >>= 1) {
            const float oa = __shfl_xor(ba, m);
            const float os = __shfl_xor(bsg, m);
            const float oi = __shfl_xor(bi, m);
            cmax(ba, bsg, bi, oa, os, oi);
        }
        if (lane == 0) l2w[(b << 8) + atomg] = make_float4(ba, bsg, bi, 0.f);
    }
}

// Head; blocks with s==15 compute the final select inline from l2 parity buf.
__global__ __launch_bounds__(128) void k_head(const int* __restrict__ pos_a,
                                              const int* __restrict__ atom_a,
                                              const float* __restrict__ amp_a,
                                              const float4* __restrict__ l2,
                                              const float* __restrict__ wpa,
                                              const float* __restrict__ bpa,
                                              const float* __restrict__ wat,
                                              const float* __restrict__ bat,
                                              const float* __restrict__ wr,
                                              const float* __restrict__ br,
                                              float* __restrict__ out) {
    const int s = blockIdx.x, b = blockIdx.y;
    const int o = threadIdx.x;
    __shared__ float4 hred[2];
    __shared__ int sh_pos, sh_atom;
    __shared__ float sh_amp;
    int pos, atom; float amp;
    if (s == NSTEP - 1) {
        const float4* l2r = l2 + ((NSTEP - 1) & 1) * (BATCH * NATOM);
        float ba = -1.f, bsg = 0.f, bi = 3.0e7f;
        const float4 e0 = l2r[(b << 8) + o];
        const float4 e1 = l2r[(b << 8) + 128 + o];
        cmax(ba, bsg, bi, e0.x, e0.y, e0.z);
        cmax(ba, bsg, bi, e1.x, e1.y, e1.z);
#pragma unroll
        for (int m = 32; m >= 1; m >>= 1) {
            const float oa = __shfl_xor(ba, m);
            const float os = __shfl_xor(bsg, m);
            const float oi = __shfl_xor(bi, m);
            cmax(ba, bsg, bi, oa, os, oi);
        }
        if ((o & 63) == 0) hred[o >> 6] = make_float4(ba, bsg, bi, 0.f);
        __syncthreads();
        if (o == 0) {
            float4 r = hred[0];
            const float4 q = hred[1];
            if (q.x > r.x || (q.x == r.x && q.z < r.z)) r = q;
            const int idx = (int)r.z;
            sh_atom = idx / TOUT;
            sh_pos = idx - sh_atom * TOUT;
            sh_amp = r.y;
        }
        __syncthreads();
        pos = sh_pos; atom = sh_atom; amp = sh_amp;
    } else {
        pos  = pos_a[s * BATCH + b];
        atom = atom_a[s * BATCH + b];
        amp  = amp_a[s * BATCH + b];
    }
    const float posn = (float)pos / 32513.0f;
    float sum = br[o];
    for (int c = 0; c < 128; ++c) {
        const float pa = wpa[c * 2] * posn + wpa[c * 2 + 1] * amp + bpa[c];
        const float at = wat[c * 256 + atom] + bat[c];
        sum += wr[o * 256 + c] * pa + wr[o * 256 + 128 + c] * at;
    }
    out[(b * 128 + o) * NSTEP + s] = sum;
}

extern "C" void kernel_launch(void* const* d_in, const int* in_sizes, int n_in,
                              void* d_out, int out_size, void* d_ws, size_t ws_size,
                              hipStream_t stream) {
    const float* x   = (const float*)d_in[0];
    const float* d   = (const float*)d_in[1];
    const float* wpa = (const float*)d_in[2];
    const float* bpa = (const float*)d_in[3];
    const float* wat = (const float*)d_in[4];
    const float* bat = (const float*)d_in[5];
    const float* wr  = (const float*)d_in[6];
    const float* br  = (const float*)d_in[7];
    float* out = (float*)d_out;

    char* ws = (char*)d_ws;
    float2* bm     = (float2*)ws;                                   // 4,177,920
    float4* l2     = (float4*)(ws + 4177920);                       // 65,536
    int*    pos_a  = (int*)(ws + 4243456);                          // 512
    int*    atom_a = (int*)(ws + 4243968);                          // 512
    float*  amp_a  = (float*)(ws + 4244480);                        // 512
    uint4*  dhF    = (uint4*)(ws + 4244992);                        // 131,072
    uint4*  dlF    = (uint4*)(ws + 4376064);                        // 131,072
    // union region @4507136: xhl4 (4,227,072) dead after k_init; resid0/1 after
    uint4*  xhl4   = (uint4*)(ws + 4507136);
    float*  resid0 = (float*)(ws + 4507136);                        // 1,048,576
    float*  resid1 = (float*)(ws + 5555712);                        // 1,048,576

    const int prep_n = BATCH * XSTR + NATOM * 32;
    k_prep<<<(prep_n + 255) / 256, 256, 0, stream>>>(x, d, xhl4, dhF, dlF);
    k_init<<<dim3(64, 4, 8), 256, 0, stream>>>(xhl4, dhF, dlF, bm);
    k_lvl2<<<dim3(32, 8), 256, 0, stream>>>(bm, l2);
    // xhl4 dead from here; resid buffers reuse its space (stream-ordered)
    hipMemcpyAsync(resid0, x, (size_t)BATCH * NS * sizeof(float),
                   hipMemcpyDeviceToDevice, stream);
    for (int st = 0; st < NSTEP - 1; ++st) {
        float* rs = (st & 1) ? resid1 : resid0;
        float* rd = (st & 1) ? resid0 : resid1;
        k_step<<<dim3(32, 8), 512, 0, stream>>>(d, rs, rd, bm, l2,
                                                pos_a, atom_a, amp_a, st);
    }
    k_head<<<dim3(16, 8), 128, 0, stream>>>(pos_a, atom_a, amp_a, l2,
                                            wpa, bpa, wat, bat, wr, br, out);
}

// Round 9
// 497.754 us; speedup vs baseline: 1.0243x; 1.0243x over previous
//
#include <hip/hip_runtime.h>
#include <hip/hip_bf16.h>
#include <float.h>

#define NS 32768
#define KER 256
#define TOUT 32513
#define NATOM 256
#define NSTEP 16
#define BATCH 8
#define NBLK 255
#define XSTR 33024   // NS + 256 pad (zero-filled)
#define SW4(i) ((i) + (((i) >> 5) << 2))

typedef __attribute__((ext_vector_type(8))) _Float16 half8;
typedef __attribute__((ext_vector_type(16))) float f32x16;
typedef __attribute__((ext_vector_type(4))) unsigned int uint4v;

__device__ __forceinline__ void cmax(float& ba, float& bs, float& bi,
                                     float oa, float os, float oi) {
    if (oa > ba || (oa == ba && oi < bi)) { ba = oa; bs = os; bi = oi; }
}

__device__ __forceinline__ void fma8(float acc[8], float4 dA, float4 dB,
                                     float4 w0, float4 w1, float4 w2, float4 w3) {
    float w[16] = {w0.x,w0.y,w0.z,w0.w, w1.x,w1.y,w1.z,w1.w,
                   w2.x,w2.y,w2.z,w2.w, w3.x,w3.y,w3.z,w3.w};
    float dv[8] = {dA.x,dA.y,dA.z,dA.w, dB.x,dB.y,dB.z,dB.w};
#pragma unroll
    for (int i = 0; i < 8; ++i)
#pragma unroll
        for (int j = 0; j < 8; ++j)
            acc[j] = fmaf(dv[i], w[i + j], acc[j]);
}

__device__ __forceinline__ unsigned short f16hi(float v) {
    return __builtin_bit_cast(unsigned short, (_Float16)v);
}
__device__ __forceinline__ unsigned short f16lo(float v) {
    const _Float16 h = (_Float16)v;
    return __builtin_bit_cast(unsigned short, (_Float16)(v - (float)h));
}

// xhl4[i] = {hi01, hi23, lo01, lo23} f16 of x[i..i+3] (redundant quads, one
// b128 read covers hi+lo of 4 elems). dhF/dlF fragment-major.
__global__ __launch_bounds__(256) void k_prep(const float* __restrict__ x,
                                              const float* __restrict__ d,
                                              uint4* __restrict__ xhl4,
                                              uint4* __restrict__ dhF,
                                              uint4* __restrict__ dlF) {
    const int gid = blockIdx.x * 256 + threadIdx.x;
    const int NXE = BATCH * XSTR;
    if (gid < NXE) {
        const int b = gid / XSTR, i = gid - b * XSTR;
        float v[4];
#pragma unroll
        for (int u = 0; u < 4; ++u)
            v[u] = (i + u < NS) ? x[b * NS + i + u] : 0.f;
        uint4 q;
        q.x = (unsigned int)f16hi(v[0]) | ((unsigned int)f16hi(v[1]) << 16);
        q.y = (unsigned int)f16hi(v[2]) | ((unsigned int)f16hi(v[3]) << 16);
        q.z = (unsigned int)f16lo(v[0]) | ((unsigned int)f16lo(v[1]) << 16);
        q.w = (unsigned int)f16lo(v[2]) | ((unsigned int)f16lo(v[3]) << 16);
        xhl4[gid] = q;
    } else {
        const int j = gid - NXE;
        if (j < NATOM * 32) {
            const int kg = j >> 8, atom = j & 255;
            const float* dp = d + atom * 256 + (kg << 3);
            uint4 hw, lw;
            hw.x = (unsigned int)f16hi(dp[0]) | ((unsigned int)f16hi(dp[1]) << 16);
            hw.y = (unsigned int)f16hi(dp[2]) | ((unsigned int)f16hi(dp[3]) << 16);
            hw.z = (unsigned int)f16hi(dp[4]) | ((unsigned int)f16hi(dp[5]) << 16);
            hw.w = (unsigned int)f16hi(dp[6]) | ((unsigned int)f16hi(dp[7]) << 16);
            lw.x = (unsigned int)f16lo(dp[0]) | ((unsigned int)f16lo(dp[1]) << 16);
            lw.y = (unsigned int)f16lo(dp[2]) | ((unsigned int)f16lo(dp[3]) << 16);
            lw.z = (unsigned int)f16lo(dp[4]) | ((unsigned int)f16lo(dp[5]) << 16);
            lw.w = (unsigned int)f16lo(dp[6]) | ((unsigned int)f16lo(dp[7]) << 16);
            dhF[(kg << 8) + atom] = hw;
            dlF[(kg << 8) + atom] = lw;
        }
    }
}

// 32x32x16_f16 MFMA correlation, 2m x 2n register tile (64 atoms x 64 t / wave).
// grid (128 t-chunks of 256, 4 atom-groups of 64, 8 b), block 256 (4 waves).
// Block covers 256 t = 2 bm blocks; waves {2p,2p+1} combine into blk 2c+p.
// r8 lesson: 8 f32x16 accs -> 264 unified regs -> 1 wave/SIMD. 4 accs -> ~140.
__global__ __launch_bounds__(256) void k_init(const uint4* __restrict__ xhl4,
                                              const uint4* __restrict__ dhF,
                                              const uint4* __restrict__ dlF,
                                              float2* __restrict__ bm) {
    const int c = blockIdx.x, mg = blockIdx.y, b = blockIdx.z;
    const int tid = threadIdx.x;
    const int w = tid >> 6, l = tid & 63;
    const int n = l & 31, h = l >> 5;
    __shared__ uint4 xw[512];        // 256-t window + 252 tail, packed quads
    __shared__ float4 wmax[4][64];
    const int t0 = c << 8;
    xw[tid] = xhl4[b * XSTR + t0 + tid];
    xw[tid + 256] = xhl4[b * XSTR + t0 + 256 + tid];
    __syncthreads();

    f32x16 acc00, acc01, acc10, acc11;
#pragma unroll
    for (int j = 0; j < 16; ++j) { acc00[j] = 0.f; acc01[j] = 0.f;
                                   acc10[j] = 0.f; acc11[j] = 0.f; }

    const int abase = (mg << 6) + n;
    const int sbb = (w << 6) + n + (h << 3);
#pragma unroll 2
    for (int kk = 0; kk < 16; ++kk) {
        const int kg = (kk << 1) + h;
        const half8 ah0 = __builtin_bit_cast(half8, dhF[(kg << 8) + abase]);
        const half8 al0 = __builtin_bit_cast(half8, dlF[(kg << 8) + abase]);
        const half8 ah1 = __builtin_bit_cast(half8, dhF[(kg << 8) + abase + 32]);
        const half8 al1 = __builtin_bit_cast(half8, dlF[(kg << 8) + abase + 32]);
        {
            const int s0 = sbb + (kk << 4);
            const uint4 q0 = xw[s0], q1 = xw[s0 + 4];
            const uint4v hv = {q0.x, q0.y, q1.x, q1.y};
            const uint4v lv = {q0.z, q0.w, q1.z, q1.w};
            const half8 bh = __builtin_bit_cast(half8, hv);
            const half8 bl = __builtin_bit_cast(half8, lv);
            acc00 = __builtin_amdgcn_mfma_f32_32x32x16_f16(ah0, bl, acc00, 0, 0, 0);
            acc00 = __builtin_amdgcn_mfma_f32_32x32x16_f16(al0, bh, acc00, 0, 0, 0);
            acc00 = __builtin_amdgcn_mfma_f32_32x32x16_f16(ah0, bh, acc00, 0, 0, 0);
            acc10 = __builtin_amdgcn_mfma_f32_32x32x16_f16(ah1, bl, acc10, 0, 0, 0);
            acc10 = __builtin_amdgcn_mfma_f32_32x32x16_f16(al1, bh, acc10, 0, 0, 0);
            acc10 = __builtin_amdgcn_mfma_f32_32x32x16_f16(ah1, bh, acc10, 0, 0, 0);
        }
        {
            const int s0 = sbb + 32 + (kk << 4);
            const uint4 q0 = xw[s0], q1 = xw[s0 + 4];
            const uint4v hv = {q0.x, q0.y, q1.x, q1.y};
            const uint4v lv = {q0.z, q0.w, q1.z, q1.w};
            const half8 bh = __builtin_bit_cast(half8, hv);
            const half8 bl = __builtin_bit_cast(half8, lv);
            acc01 = __builtin_amdgcn_mfma_f32_32x32x16_f16(ah0, bl, acc01, 0, 0, 0);
            acc01 = __builtin_amdgcn_mfma_f32_32x32x16_f16(al0, bh, acc01, 0, 0, 0);
            acc01 = __builtin_amdgcn_mfma_f32_32x32x16_f16(ah0, bh, acc01, 0, 0, 0);
            acc11 = __builtin_amdgcn_mfma_f32_32x32x16_f16(ah1, bl, acc11, 0, 0, 0);
            acc11 = __builtin_amdgcn_mfma_f32_32x32x16_f16(al1, bh, acc11, 0, 0, 0);
            acc11 = __builtin_amdgcn_mfma_f32_32x32x16_f16(ah1, bh, acc11, 0, 0, 0);
        }
    }

    // Epilogue: C col=lane&31 (t), row=(r&3)+8*(r>>2)+4*h (atom within 32).
    const int tb = t0 + (w << 6) + n;
#pragma unroll
    for (int mt = 0; mt < 2; ++mt) {
#pragma unroll
        for (int r = 0; r < 16; ++r) {
            const int amt = (mt << 5) + (r & 3) + ((r >> 2) << 3) + (h << 2);
            const float fa = (float)(((mg << 6) + amt) * TOUT);
            const float v0 = (mt == 0) ? acc00[r] : acc10[r];
            const float v1 = (mt == 0) ? acc01[r] : acc11[r];
            float ba = -1.f, bsg = 0.f, bi = 3.0e7f;
            if (tb < TOUT) { ba = fabsf(v0); bsg = v0; bi = fa + (float)tb; }
            if (tb + 32 < TOUT) {
                const float a1 = fabsf(v1);
                if (a1 > ba) { ba = a1; bsg = v1; bi = fa + (float)(tb + 32); }
            }
#pragma unroll
            for (int m = 1; m <= 16; m <<= 1) {
                const float oa = __shfl_xor(ba, m, 32);
                const float os = __shfl_xor(bsg, m, 32);
                const float oi = __shfl_xor(bi, m, 32);
                cmax(ba, bsg, bi, oa, os, oi);
            }
            if (n == 0) wmax[w][amt] = make_float4(ba, bsg, bi, 0.f);
        }
    }
    __syncthreads();
    if (tid < 128) {
        const int a = tid & 63, p = tid >> 6;
        const float4 e1 = wmax[(p << 1)][a];
        const float4 e2 = wmax[(p << 1) + 1][a];
        float ba = e1.x, bsg = e1.y, bi = e1.z;
        cmax(ba, bsg, bi, e2.x, e2.y, e2.z);
        const int blk = (c << 1) + p;
        if (blk < NBLK)
            bm[(size_t)((b << 8) + (mg << 6) + a) * NBLK + blk] = make_float2(bsg, bi);
    }
}

// Per-atom (level-2) maxima over all blocks -> l2 buffer 0.
__global__ __launch_bounds__(256) void k_lvl2(const float2* __restrict__ bm,
                                              float4* __restrict__ l2) {
    const int b = blockIdx.y;
    const int oglob = blockIdx.x * 8 + (threadIdx.x >> 5);
    const int lane = threadIdx.x & 31;
    const float2* row = bm + (size_t)(b * NATOM + oglob) * NBLK;
    float ba = -1.f, bsg = 0.f, bi = 3.0e7f;
    for (int i = lane; i < NBLK; i += 32) {
        const float2 e = row[i];
        cmax(ba, bsg, bi, fabsf(e.x), e.x, e.y);
    }
#pragma unroll
    for (int m = 16; m >= 1; m >>= 1) {
        const float oa = __shfl_xor(ba, m, 32);
        const float os = __shfl_xor(bsg, m, 32);
        const float oi = __shfl_xor(bi, m, 32);
        cmax(ba, bsg, bi, oa, os, oi);
    }
    if (lane == 0) l2[(b << 8) + oglob] = make_float4(ba, bsg, bi, 0.f);
}

// One MP step with persistent double-buffered residual (unchanged from r7/r8).
__global__ __launch_bounds__(512) void k_step(const float* __restrict__ d,
                                              const float* __restrict__ resid_src,
                                              float* __restrict__ resid_dst,
                                              float2* __restrict__ bm,
                                              float4* __restrict__ l2,
                                              int* __restrict__ pos_a,
                                              int* __restrict__ atom_a,
                                              float* __restrict__ amp_a,
                                              int step) {
    const int og = blockIdx.x, b = blockIdx.y;
    const int tid = threadIdx.x;
    const int wave = tid >> 6, lane = tid & 63;
    __shared__ float dt[2048];
    __shared__ float rsu[1024];
    __shared__ float4 sred[8];
    __shared__ float4 upd[8][5];
    __shared__ int sh_pos, sh_atom;
    __shared__ float sh_amp;

    ((float4*)dt)[tid] = ((const float4*)(d + og * 2048))[tid];
    const float4* l2r = l2 + (step & 1) * (BATCH * NATOM);
    float4*       l2w = l2 + ((step + 1) & 1) * (BATCH * NATOM);

    {
        float ba = -1.f, bsg = 0.f, bi = 3.0e7f;
        if (tid < 256) {
            const float4 e = l2r[(b << 8) + tid];
            ba = e.x; bsg = e.y; bi = e.z;
        }
#pragma unroll
        for (int m = 32; m >= 1; m >>= 1) {
            const float oa = __shfl_xor(ba, m);
            const float os = __shfl_xor(bsg, m);
            const float oi = __shfl_xor(bi, m);
            cmax(ba, bsg, bi, oa, os, oi);
        }
        if (lane == 0) sred[wave] = make_float4(ba, bsg, bi, 0.f);
    }
    __syncthreads();
    if (tid == 0) {
        float4 r = sred[0];
#pragma unroll
        for (int i = 1; i < 8; ++i) {
            const float4 q = sred[i];
            if (q.x > r.x || (q.x == r.x && q.z < r.z)) r = q;
        }
        const int idx = (int)r.z;
        const int atom = idx / TOUT;
        const int pos = idx - atom * TOUT;
        sh_pos = pos; sh_atom = atom; sh_amp = r.y;
        if (og == 0) {
            pos_a[step * BATCH + b] = pos;
            atom_a[step * BATCH + b] = atom;
            amp_a[step * BATCH + b] = r.y;
        }
    }
    __syncthreads();
    const int p = sh_pos, atom_s = sh_atom;
    const float amp = sh_amp;

    for (int i = tid; i < 1024; i += 512) {
        const int g = (og << 10) + i;
        float v = resid_src[(size_t)b * NS + g];
        const int off = g - p;
        if (off >= 0 && off < KER)
            v = __fsub_rn(v, __fmul_rn(amp, d[atom_s * KER + off]));
        resid_dst[(size_t)b * NS + g] = v;
    }

    int tlo = p - 255; if (tlo < 0) tlo = 0;
    int thi = p + 255; if (thi > TOUT - 1) thi = TOUT - 1;
    const int bs0 = tlo >> 7, be0 = thi >> 7;
    const int rbase = bs0 << 7;
    const int nblks = be0 - bs0 + 1;
    const int rlen = (nblks << 7) + 255;
    for (int i = tid; i < rlen; i += 512) {
        const int g = rbase + i;
        float v = (g < NS) ? resid_src[(size_t)b * NS + g] : 0.f;
        const int off = g - p;
        if (g < NS && off >= 0 && off < KER)
            v = __fsub_rn(v, __fmul_rn(amp, d[atom_s * KER + off]));
        rsu[SW4(i)] = v;
    }
    __syncthreads();

    const int lg = lane >> 4, l16 = lane & 15;
    const float* dp = dt + (wave << 8) + (lg << 6);
    const int atomg = (og << 3) + wave;
    for (int bb = 0; bb < nblks; ++bb) {
        const int blk = bs0 + bb;
        const int t0r = (bb << 7) + (l16 << 3) + (lg << 6);
        float acc[8];
#pragma unroll
        for (int j = 0; j < 8; ++j) acc[j] = 0.f;
        float4 A0 = *(const float4*)(rsu + SW4(t0r));
        float4 A1 = *(const float4*)(rsu + SW4(t0r + 4));
        float4 B0 = *(const float4*)(rsu + SW4(t0r + 8));
        float4 B1 = *(const float4*)(rsu + SW4(t0r + 12));
#pragma unroll
        for (int kk = 0; kk < 64; kk += 16) {
            const float4 d0 = *(const float4*)(dp + kk);
            const float4 d1 = *(const float4*)(dp + kk + 4);
            const float4 N0 = *(const float4*)(rsu + SW4(t0r + kk + 16));
            const float4 N1 = *(const float4*)(rsu + SW4(t0r + kk + 20));
            fma8(acc, d0, d1, A0, A1, B0, B1);
            const float4 d2 = *(const float4*)(dp + kk + 8);
            const float4 d3 = *(const float4*)(dp + kk + 12);
            const float4 M0 = *(const float4*)(rsu + SW4(t0r + kk + 24));
            const float4 M1 = *(const float4*)(rsu + SW4(t0r + kk + 28));
            fma8(acc, d2, d3, B0, B1, N0, N1);
            A0 = N0; A1 = N1; B0 = M0; B1 = M1;
        }
#pragma unroll
        for (int j = 0; j < 8; ++j) {
            acc[j] += __shfl_xor(acc[j], 16);
            acc[j] += __shfl_xor(acc[j], 32);
        }
        float ba = -1.f, bsg = 0.f, bi = 3.0e7f;
        const int tbp = rbase + (bb << 7) + (l16 << 3);
#pragma unroll
        for (int j = 0; j < 8; ++j) {
            const int t = tbp + j;
            const float av = fabsf(acc[j]);
            if (t < TOUT && av > ba) { ba = av; bsg = acc[j]; bi = (float)(atomg * TOUT + t); }
        }
#pragma unroll
        for (int m = 32; m >= 1; m >>= 1) {
            const float oa = __shfl_xor(ba, m);
            const float os = __shfl_xor(bsg, m);
            const float oi = __shfl_xor(bi, m);
            cmax(ba, bsg, bi, oa, os, oi);
        }
        if (lane == 0) {
            bm[(size_t)(b * NATOM + atomg) * NBLK + blk] = make_float2(bsg, bi);
            upd[wave][bb] = make_float4(ba, bsg, bi, 0.f);
        }
    }
    __syncthreads();

    {
        float ba = -1.f, bsg = 0.f, bi = 3.0e7f;
        const float2* row = bm + (size_t)(b * NATOM + atomg) * NBLK;
        for (int i = lane; i < NBLK; i += 64) {
            if (i >= bs0 && i <= be0) {
                const float4 e2 = upd[wave][i - bs0];
                cmax(ba, bsg, bi, e2.x, e2.y, e2.z);
            } else {
                const float2 e2 = row[i];
                cmax(ba, bsg, bi, fabsf(e2.x), e2.x, e2.y);
            }
        }
#pragma unroll
        for (int m = 32; m >= 1; m >>= 1) {
            const float oa = __shfl_xor(ba, m);
            const float os = __shfl_xor(bsg, m);
            const float oi = __shfl_xor(bi, m);
            cmax(ba, bsg, bi, oa, os, oi);
        }
        if (lane == 0) l2w[(b << 8) + atomg] = make_float4(ba, bsg, bi, 0.f);
    }
}

// Head; blocks with s==15 compute the final select inline from l2 parity buf.
__global__ __launch_bounds__(128) void k_head(const int* __restrict__ pos_a,
                                              const int* __restrict__ atom_a,
                                              const float* __restrict__ amp_a,
                                              const float4* __restrict__ l2,
                                              const float* __restrict__ wpa,
                                              const float* __restrict__ bpa,
                                              const float* __restrict__ wat,
                                              const float* __restrict__ bat,
                                              const float* __restrict__ wr,
                                              const float* __restrict__ br,
                                              float* __restrict__ out) {
    const int s = blockIdx.x, b = blockIdx.y;
    const int o = threadIdx.x;
    __shared__ float4 hred[2];
    __shared__ int sh_pos, sh_atom;
    __shared__ float sh_amp;
    int pos, atom; float amp;
    if (s == NSTEP - 1) {
        const float4* l2r = l2 + ((NSTEP - 1) & 1) * (BATCH * NATOM);
        float ba = -1.f, bsg = 0.f, bi = 3.0e7f;
        const float4 e0 = l2r[(b << 8) + o];
        const float4 e1 = l2r[(b << 8) + 128 + o];
        cmax(ba, bsg, bi, e0.x, e0.y, e0.z);
        cmax(ba, bsg, bi, e1.x, e1.y, e1.z);
#pragma unroll
        for (int m = 32; m >= 1; m >>= 1) {
            const float oa = __shfl_xor(ba, m);
            const float os = __shfl_xor(bsg, m);
            const float oi = __shfl_xor(bi, m);
            cmax(ba, bsg, bi, oa, os, oi);
        }
        if ((o & 63) == 0) hred[o >> 6] = make_float4(ba, bsg, bi, 0.f);
        __syncthreads();
        if (o == 0) {
            float4 r = hred[0];
            const float4 q = hred[1];
            if (q.x > r.x || (q.x == r.x && q.z < r.z)) r = q;
            const int idx = (int)r.z;
            sh_atom = idx / TOUT;
            sh_pos = idx - sh_atom * TOUT;
            sh_amp = r.y;
        }
        __syncthreads();
        pos = sh_pos; atom = sh_atom; amp = sh_amp;
    } else {
        pos  = pos_a[s * BATCH + b];
        atom = atom_a[s * BATCH + b];
        amp  = amp_a[s * BATCH + b];
    }
    const float posn = (float)pos / 32513.0f;
    float sum = br[o];
    for (int c = 0; c < 128; ++c) {
        const float pa = wpa[c * 2] * posn + wpa[c * 2 + 1] * amp + bpa[c];
        const float at = wat[c * 256 + atom] + bat[c];
        sum += wr[o * 256 + c] * pa + wr[o * 256 + 128 + c] * at;
    }
    out[(b * 128 + o) * NSTEP + s] = sum;
}

extern "C" void kernel_launch(void* const* d_in, const int* in_sizes, int n_in,
                              void* d_out, int out_size, void* d_ws, size_t ws_size,
                              hipStream_t stream) {
    const float* x   = (const float*)d_in[0];
    const float* d   = (const float*)d_in[1];
    const float* wpa = (const float*)d_in[2];
    const float* bpa = (const float*)d_in[3];
    const float* wat = (const float*)d_in[4];
    const float* bat = (const float*)d_in[5];
    const float* wr  = (const float*)d_in[6];
    const float* br  = (const float*)d_in[7];
    float* out = (float*)d_out;

    char* ws = (char*)d_ws;
    float2* bm     = (float2*)ws;                                   // 4,177,920
    float4* l2     = (float4*)(ws + 4177920);                       // 65,536
    int*    pos_a  = (int*)(ws + 4243456);                          // 512
    int*    atom_a = (int*)(ws + 4243968);                          // 512
    float*  amp_a  = (float*)(ws + 4244480);                        // 512
    uint4*  dhF    = (uint4*)(ws + 4244992);                        // 131,072
    uint4*  dlF    = (uint4*)(ws + 4376064);                        // 131,072
    // union region @4507136: xhl4 (4,227,072) dead after k_init; resid0/1 after
    uint4*  xhl4   = (uint4*)(ws + 4507136);
    float*  resid0 = (float*)(ws + 4507136);                        // 1,048,576
    float*  resid1 = (float*)(ws + 5555712);                        // 1,048,576

    const int prep_n = BATCH * XSTR + NATOM * 32;
    k_prep<<<(prep_n + 255) / 256, 256, 0, stream>>>(x, d, xhl4, dhF, dlF);
    k_init<<<dim3(128, 4, 8), 256, 0, stream>>>(xhl4, dhF, dlF, bm);
    k_lvl2<<<dim3(32, 8), 256, 0, stream>>>(bm, l2);
    // xhl4 dead from here; resid buffers reuse its space (stream-ordered)
    hipMemcpyAsync(resid0, x, (size_t)BATCH * NS * sizeof(float),
                   hipMemcpyDeviceToDevice, stream);
    for (int st = 0; st < NSTEP - 1; ++st) {
        float* rs = (st & 1) ? resid1 : resid0;
        float* rd = (st & 1) ? resid0 : resid1;
        k_step<<<dim3(32, 8), 512, 0, stream>>>(d, rs, rd, bm, l2,
                                                pos_a, atom_a, amp_a, st);
    }
    k_head<<<dim3(16, 8), 128, 0, stream>>>(pos_a, atom_a, amp_a, l2,
                                            wpa, bpa, wat, bat, wr, br, out);
}

// Round 10
// 407.842 us; speedup vs baseline: 1.2501x; 1.2205x over previous
//
#include <hip/hip_runtime.h>
#include <hip/hip_bf16.h>
#include <float.h>

#define NS 32768
#define KER 256
#define TOUT 32513
#define NATOM 256
#define NSTEP 16
#define BATCH 8
#define NBLK 255
#define XSTR 33024   // NS + 256 pad (zero-filled)
#define SW4(i) ((i) + (((i) >> 5) << 2))

typedef __attribute__((ext_vector_type(8))) _Float16 half8;
typedef __attribute__((ext_vector_type(16))) float f32x16;
typedef __attribute__((ext_vector_type(4))) unsigned int uint4v;

__device__ __forceinline__ void cmax(float& ba, float& bs, float& bi,
                                     float oa, float os, float oi) {
    if (oa > ba || (oa == ba && oi < bi)) { ba = oa; bs = os; bi = oi; }
}

__device__ __forceinline__ void fma8(float acc[8], float4 dA, float4 dB,
                                     float4 w0, float4 w1, float4 w2, float4 w3) {
    float w[16] = {w0.x,w0.y,w0.z,w0.w, w1.x,w1.y,w1.z,w1.w,
                   w2.x,w2.y,w2.z,w2.w, w3.x,w3.y,w3.z,w3.w};
    float dv[8] = {dA.x,dA.y,dA.z,dA.w, dB.x,dB.y,dB.z,dB.w};
#pragma unroll
    for (int i = 0; i < 8; ++i)
#pragma unroll
        for (int j = 0; j < 8; ++j)
            acc[j] = fmaf(dv[i], w[i + j], acc[j]);
}

__device__ __forceinline__ unsigned short f16hi(float v) {
    return __builtin_bit_cast(unsigned short, (_Float16)v);
}
__device__ __forceinline__ unsigned short f16lo(float v) {
    const _Float16 h = (_Float16)v;
    return __builtin_bit_cast(unsigned short, (_Float16)(v - (float)h));
}

// xhl4[i] = {hi01, hi23, lo01, lo23} f16 of x[i..i+3] (redundant quads, one
// b128 read covers hi+lo of 4 elems). dhF/dlF fragment-major.
__global__ __launch_bounds__(256) void k_prep(const float* __restrict__ x,
                                              const float* __restrict__ d,
                                              uint4* __restrict__ xhl4,
                                              uint4* __restrict__ dhF,
                                              uint4* __restrict__ dlF) {
    const int gid = blockIdx.x * 256 + threadIdx.x;
    const int NXE = BATCH * XSTR;
    if (gid < NXE) {
        const int b = gid / XSTR, i = gid - b * XSTR;
        float v[4];
#pragma unroll
        for (int u = 0; u < 4; ++u)
            v[u] = (i + u < NS) ? x[b * NS + i + u] : 0.f;
        uint4 q;
        q.x = (unsigned int)f16hi(v[0]) | ((unsigned int)f16hi(v[1]) << 16);
        q.y = (unsigned int)f16hi(v[2]) | ((unsigned int)f16hi(v[3]) << 16);
        q.z = (unsigned int)f16lo(v[0]) | ((unsigned int)f16lo(v[1]) << 16);
        q.w = (unsigned int)f16lo(v[2]) | ((unsigned int)f16lo(v[3]) << 16);
        xhl4[gid] = q;
    } else {
        const int j = gid - NXE;
        if (j < NATOM * 32) {
            const int kg = j >> 8, atom = j & 255;
            const float* dp = d + atom * 256 + (kg << 3);
            uint4 hw, lw;
            hw.x = (unsigned int)f16hi(dp[0]) | ((unsigned int)f16hi(dp[1]) << 16);
            hw.y = (unsigned int)f16hi(dp[2]) | ((unsigned int)f16hi(dp[3]) << 16);
            hw.z = (unsigned int)f16hi(dp[4]) | ((unsigned int)f16hi(dp[5]) << 16);
            hw.w = (unsigned int)f16hi(dp[6]) | ((unsigned int)f16hi(dp[7]) << 16);
            lw.x = (unsigned int)f16lo(dp[0]) | ((unsigned int)f16lo(dp[1]) << 16);
            lw.y = (unsigned int)f16lo(dp[2]) | ((unsigned int)f16lo(dp[3]) << 16);
            lw.z = (unsigned int)f16lo(dp[4]) | ((unsigned int)f16lo(dp[5]) << 16);
            lw.w = (unsigned int)f16lo(dp[6]) | ((unsigned int)f16lo(dp[7]) << 16);
            dhF[(kg << 8) + atom] = hw;
            dlF[(kg << 8) + atom] = lw;
        }
    }
}

// 32x32x16_f16 MFMA correlation, 2m x 2n tile, diagonal-B register FIFO
// (Toeplitz: B(nt=1,kk) == B(nt=0,kk+2) -> 2 LDS b128/kk instead of 4).
// grid (128 t-chunks of 256, 4 atom-groups of 64, 8 b), block 256 (4 waves).
// Epilogue: u64 argmax keys (abs || ~idx || sign) -> 1-value shuffle ladder.
__global__ __launch_bounds__(256) void k_init(const uint4* __restrict__ xhl4,
                                              const uint4* __restrict__ dhF,
                                              const uint4* __restrict__ dlF,
                                              float2* __restrict__ bm) {
    const int c = blockIdx.x, mg = blockIdx.y, b = blockIdx.z;
    const int tid = threadIdx.x;
    const int w = tid >> 6, l = tid & 63;
    const int n = l & 31, h = l >> 5;
    __shared__ uint4 xw[512];                 // 256-t window + 252 tail
    __shared__ unsigned long long wmax[4][64];
    const int t0 = c << 8;
    xw[tid] = xhl4[b * XSTR + t0 + tid];
    xw[tid + 256] = xhl4[b * XSTR + t0 + 256 + tid];
    __syncthreads();

    f32x16 acc00, acc01, acc10, acc11;
#pragma unroll
    for (int j = 0; j < 16; ++j) { acc00[j] = 0.f; acc01[j] = 0.f;
                                   acc10[j] = 0.f; acc11[j] = 0.f; }

    const int abase = (mg << 6) + n;
    const int sbb = (w << 6) + n + (h << 3);

    // B fragment FIFO: slot kk&3 holds F(kk); live window [kk, kk+2].
    half8 fbh[4], fbl[4];
    {
        const uint4 q0 = xw[sbb], q1 = xw[sbb + 4];
        const uint4v hv = {q0.x, q0.y, q1.x, q1.y};
        const uint4v lv = {q0.z, q0.w, q1.z, q1.w};
        fbh[0] = __builtin_bit_cast(half8, hv);
        fbl[0] = __builtin_bit_cast(half8, lv);
    }
    {
        const uint4 q0 = xw[sbb + 16], q1 = xw[sbb + 20];
        const uint4v hv = {q0.x, q0.y, q1.x, q1.y};
        const uint4v lv = {q0.z, q0.w, q1.z, q1.w};
        fbh[1] = __builtin_bit_cast(half8, hv);
        fbl[1] = __builtin_bit_cast(half8, lv);
    }

#pragma unroll 4
    for (int kk = 0; kk < 16; ++kk) {
        const int kg = (kk << 1) + h;
        const half8 ah0 = __builtin_bit_cast(half8, dhF[(kg << 8) + abase]);
        const half8 al0 = __builtin_bit_cast(half8, dlF[(kg << 8) + abase]);
        const half8 ah1 = __builtin_bit_cast(half8, dhF[(kg << 8) + abase + 32]);
        const half8 al1 = __builtin_bit_cast(half8, dlF[(kg << 8) + abase + 32]);
        {   // load F(kk+2) into slot (kk+2)&3  (also the nt=1 fragment this iter)
            const int sN = sbb + ((kk + 2) << 4);
            const uint4 q0 = xw[sN], q1 = xw[sN + 4];
            const uint4v hv = {q0.x, q0.y, q1.x, q1.y};
            const uint4v lv = {q0.z, q0.w, q1.z, q1.w};
            fbh[(kk + 2) & 3] = __builtin_bit_cast(half8, hv);
            fbl[(kk + 2) & 3] = __builtin_bit_cast(half8, lv);
        }
        const half8 b0h = fbh[kk & 3],       b0l = fbl[kk & 3];
        const half8 b1h = fbh[(kk + 2) & 3], b1l = fbl[(kk + 2) & 3];
        acc00 = __builtin_amdgcn_mfma_f32_32x32x16_f16(ah0, b0l, acc00, 0, 0, 0);
        acc00 = __builtin_amdgcn_mfma_f32_32x32x16_f16(al0, b0h, acc00, 0, 0, 0);
        acc00 = __builtin_amdgcn_mfma_f32_32x32x16_f16(ah0, b0h, acc00, 0, 0, 0);
        acc10 = __builtin_amdgcn_mfma_f32_32x32x16_f16(ah1, b0l, acc10, 0, 0, 0);
        acc10 = __builtin_amdgcn_mfma_f32_32x32x16_f16(al1, b0h, acc10, 0, 0, 0);
        acc10 = __builtin_amdgcn_mfma_f32_32x32x16_f16(ah1, b0h, acc10, 0, 0, 0);
        acc01 = __builtin_amdgcn_mfma_f32_32x32x16_f16(ah0, b1l, acc01, 0, 0, 0);
        acc01 = __builtin_amdgcn_mfma_f32_32x32x16_f16(al0, b1h, acc01, 0, 0, 0);
        acc01 = __builtin_amdgcn_mfma_f32_32x32x16_f16(ah0, b1h, acc01, 0, 0, 0);
        acc11 = __builtin_amdgcn_mfma_f32_32x32x16_f16(ah1, b1l, acc11, 0, 0, 0);
        acc11 = __builtin_amdgcn_mfma_f32_32x32x16_f16(al1, b1h, acc11, 0, 0, 0);
        acc11 = __builtin_amdgcn_mfma_f32_32x32x16_f16(ah1, b1h, acc11, 0, 0, 0);
    }

    // Epilogue: C col=lane&31 (t), row=(r&3)+8*(r>>2)+4*h (atom within 32).
    // u64 key = abs_bits<<32 | (0x7FFFFF-idx)<<1 | signbit  (max => argmax,
    // tie -> lowest idx, matching cmax semantics exactly).
    const int tb = t0 + (w << 6) + n;
#pragma unroll
    for (int mt = 0; mt < 2; ++mt) {
#pragma unroll
        for (int r = 0; r < 16; ++r) {
            const int amt = (mt << 5) + (r & 3) + ((r >> 2) << 3) + (h << 2);
            const int idx0 = ((mg << 6) + amt) * TOUT + tb;
            const float v0 = (mt == 0) ? acc00[r] : acc10[r];
            const float v1 = (mt == 0) ? acc01[r] : acc11[r];
            const unsigned int c0 = (0x7FFFFFu - (unsigned int)idx0);
            unsigned long long k0 = 0ull, k1 = 0ull;
            if (tb < TOUT)
                k0 = ((unsigned long long)__float_as_uint(fabsf(v0)) << 32)
                   | ((unsigned long long)(c0 << 1))
                   | (unsigned long long)(__float_as_uint(v0) >> 31);
            if (tb + 32 < TOUT)
                k1 = ((unsigned long long)__float_as_uint(fabsf(v1)) << 32)
                   | ((unsigned long long)((c0 - 32u) << 1))
                   | (unsigned long long)(__float_as_uint(v1) >> 31);
            unsigned long long k = (k1 > k0) ? k1 : k0;
#pragma unroll
            for (int m = 1; m <= 16; m <<= 1) {
                const unsigned long long ok = __shfl_xor(k, m, 32);
                if (ok > k) k = ok;
            }
            if (n == 0) wmax[w][amt] = k;
        }
    }
    __syncthreads();
    if (tid < 128) {
        const int a = tid & 63, p = tid >> 6;
        unsigned long long k = wmax[(p << 1)][a];
        const unsigned long long k2 = wmax[(p << 1) + 1][a];
        if (k2 > k) k = k2;
        const int blk = (c << 1) + p;
        if (blk < NBLK) {
            const float av = __uint_as_float((unsigned int)(k >> 32));
            const unsigned int lo = (unsigned int)k;
            const int idx = 0x7FFFFF - (int)((lo >> 1) & 0x7FFFFFu);
            const float bsg = (lo & 1u) ? -av : av;
            bm[(size_t)((b << 8) + (mg << 6) + a) * NBLK + blk] =
                make_float2(bsg, (float)idx);
        }
    }
}

// Per-atom (level-2) maxima over all blocks -> l2 buffer 0.
__global__ __launch_bounds__(256) void k_lvl2(const float2* __restrict__ bm,
                                              float4* __restrict__ l2) {
    const int b = blockIdx.y;
    const int oglob = blockIdx.x * 8 + (threadIdx.x >> 5);
    const int lane = threadIdx.x & 31;
    const float2* row = bm + (size_t)(b * NATOM + oglob) * NBLK;
    float ba = -1.f, bsg = 0.f, bi = 3.0e7f;
    for (int i = lane; i < NBLK; i += 32) {
        const float2 e = row[i];
        cmax(ba, bsg, bi, fabsf(e.x), e.x, e.y);
    }
#pragma unroll
    for (int m = 16; m >= 1; m >>= 1) {
        const float oa = __shfl_xor(ba, m, 32);
        const float os = __shfl_xor(bsg, m, 32);
        const float oi = __shfl_xor(bi, m, 32);
        cmax(ba, bsg, bi, oa, os, oi);
    }
    if (lane == 0) l2[(b << 8) + oglob] = make_float4(ba, bsg, bi, 0.f);
}

// One MP step with persistent double-buffered residual (unchanged from r7-r9).
__global__ __launch_bounds__(512) void k_step(const float* __restrict__ d,
                                              const float* __restrict__ resid_src,
                                              float* __restrict__ resid_dst,
                                              float2* __restrict__ bm,
                                              float4* __restrict__ l2,
                                              int* __restrict__ pos_a,
                                              int* __restrict__ atom_a,
                                              float* __restrict__ amp_a,
                                              int step) {
    const int og = blockIdx.x, b = blockIdx.y;
    const int tid = threadIdx.x;
    const int wave = tid >> 6, lane = tid & 63;
    __shared__ float dt[2048];
    __shared__ float rsu[1024];
    __shared__ float4 sred[8];
    __shared__ float4 upd[8][5];
    __shared__ int sh_pos, sh_atom;
    __shared__ float sh_amp;

    ((float4*)dt)[tid] = ((const float4*)(d + og * 2048))[tid];
    const float4* l2r = l2 + (step & 1) * (BATCH * NATOM);
    float4*       l2w = l2 + ((step + 1) & 1) * (BATCH * NATOM);

    {
        float ba = -1.f, bsg = 0.f, bi = 3.0e7f;
        if (tid < 256) {
            const float4 e = l2r[(b << 8) + tid];
            ba = e.x; bsg = e.y; bi = e.z;
        }
#pragma unroll
        for (int m = 32; m >= 1; m >>= 1) {
            const float oa = __shfl_xor(ba, m);
            const float os = __shfl_xor(bsg, m);
            const float oi = __shfl_xor(bi, m);
            cmax(ba, bsg, bi, oa, os, oi);
        }
        if (lane == 0) sred[wave] = make_float4(ba, bsg, bi, 0.f);
    }
    __syncthreads();
    if (tid == 0) {
        float4 r = sred[0];
#pragma unroll
        for (int i = 1; i < 8; ++i) {
            const float4 q = sred[i];
            if (q.x > r.x || (q.x == r.x && q.z < r.z)) r = q;
        }
        const int idx = (int)r.z;
        const int atom = idx / TOUT;
        const int pos = idx - atom * TOUT;
        sh_pos = pos; sh_atom = atom; sh_amp = r.y;
        if (og == 0) {
            pos_a[step * BATCH + b] = pos;
            atom_a[step * BATCH + b] = atom;
            amp_a[step * BATCH + b] = r.y;
        }
    }
    __syncthreads();
    const int p = sh_pos, atom_s = sh_atom;
    const float amp = sh_amp;

    for (int i = tid; i < 1024; i += 512) {
        const int g = (og << 10) + i;
        float v = resid_src[(size_t)b * NS + g];
        const int off = g - p;
        if (off >= 0 && off < KER)
            v = __fsub_rn(v, __fmul_rn(amp, d[atom_s * KER + off]));
        resid_dst[(size_t)b * NS + g] = v;
    }

    int tlo = p - 255; if (tlo < 0) tlo = 0;
    int thi = p + 255; if (thi > TOUT - 1) thi = TOUT - 1;
    const int bs0 = tlo >> 7, be0 = thi >> 7;
    const int rbase = bs0 << 7;
    const int nblks = be0 - bs0 + 1;
    const int rlen = (nblks << 7) + 255;
    for (int i = tid; i < rlen; i += 512) {
        const int g = rbase + i;
        float v = (g < NS) ? resid_src[(size_t)b * NS + g] : 0.f;
        const int off = g - p;
        if (g < NS && off >= 0 && off < KER)
            v = __fsub_rn(v, __fmul_rn(amp, d[atom_s * KER + off]));
        rsu[SW4(i)] = v;
    }
    __syncthreads();

    const int lg = lane >> 4, l16 = lane & 15;
    const float* dp = dt + (wave << 8) + (lg << 6);
    const int atomg = (og << 3) + wave;
    for (int bb = 0; bb < nblks; ++bb) {
        const int blk = bs0 + bb;
        const int t0r = (bb << 7) + (l16 << 3) + (lg << 6);
        float acc[8];
#pragma unroll
        for (int j = 0; j < 8; ++j) acc[j] = 0.f;
        float4 A0 = *(const float4*)(rsu + SW4(t0r));
        float4 A1 = *(const float4*)(rsu + SW4(t0r + 4));
        float4 B0 = *(const float4*)(rsu + SW4(t0r + 8));
        float4 B1 = *(const float4*)(rsu + SW4(t0r + 12));
#pragma unroll
        for (int kk = 0; kk < 64; kk += 16) {
            const float4 d0 = *(const float4*)(dp + kk);
            const float4 d1 = *(const float4*)(dp + kk + 4);
            const float4 N0 = *(const float4*)(rsu + SW4(t0r + kk + 16));
            const float4 N1 = *(const float4*)(rsu + SW4(t0r + kk + 20));
            fma8(acc, d0, d1, A0, A1, B0, B1);
            const float4 d2 = *(const float4*)(dp + kk + 8);
            const float4 d3 = *(const float4*)(dp + kk + 12);
            const float4 M0 = *(const float4*)(rsu + SW4(t0r + kk + 24));
            const float4 M1 = *(const float4*)(rsu + SW4(t0r + kk + 28));
            fma8(acc, d2, d3, B0, B1, N0, N1);
            A0 = N0; A1 = N1; B0 = M0; B1 = M1;
        }
#pragma unroll
        for (int j = 0; j < 8; ++j) {
            acc[j] += __shfl_xor(acc[j], 16);
            acc[j] += __shfl_xor(acc[j], 32);
        }
        float ba = -1.f, bsg = 0.f, bi = 3.0e7f;
        const int tbp = rbase + (bb << 7) + (l16 << 3);
#pragma unroll
        for (int j = 0; j < 8; ++j) {
            const int t = tbp + j;
            const float av = fabsf(acc[j]);
            if (t < TOUT && av > ba) { ba = av; bsg = acc[j]; bi = (float)(atomg * TOUT + t); }
        }
#pragma unroll
        for (int m = 32; m >= 1; m >>= 1) {
            const float oa = __shfl_xor(ba, m);
            const float os = __shfl_xor(bsg, m);
            const float oi = __shfl_xor(bi, m);
            cmax(ba, bsg, bi, oa, os, oi);
        }
        if (lane == 0) {
            bm[(size_t)(b * NATOM + atomg) * NBLK + blk] = make_float2(bsg, bi);
            upd[wave][bb] = make_float4(ba, bsg, bi, 0.f);
        }
    }
    __syncthreads();

    {
        float ba = -1.f, bsg = 0.f, bi = 3.0e7f;
        const float2* row = bm + (size_t)(b * NATOM + atomg) * NBLK;
        for (int i = lane; i < NBLK; i += 64) {
            if (i >= bs0 && i <= be0) {
                const float4 e2 = upd[wave][i - bs0];
                cmax(ba, bsg, bi, e2.x, e2.y, e2.z);
            } else {
                const float2 e2 = row[i];
                cmax(ba, bsg, bi, fabsf(e2.x), e2.x, e2.y);
            }
        }
#pragma unroll
        for (int m = 32; m >= 1; m >>= 1) {
            const float oa = __shfl_xor(ba, m);
            const float os = __shfl_xor(bsg, m);
            const float oi = __shfl_xor(bi, m);
            cmax(ba, bsg, bi, oa, os, oi);
        }
        if (lane == 0) l2w[(b << 8) + atomg] = make_float4(ba, bsg, bi, 0.f);
    }
}

// Head; blocks with s==15 compute the final select inline from l2 parity buf.
__global__ __launch_bounds__(128) void k_head(const int* __restrict__ pos_a,
                                              const int* __restrict__ atom_a,
                                              const float* __restrict__ amp_a,
                                              const float4* __restrict__ l2,
                                              const float* __restrict__ wpa,
                                              const float* __restrict__ bpa,
                                              const float* __restrict__ wat,
                                              const float* __restrict__ bat,
                                              const float* __restrict__ wr,
                                              const float* __restrict__ br,
                                              float* __restrict__ out) {
    const int s = blockIdx.x, b = blockIdx.y;
    const int o = threadIdx.x;
    __shared__ float4 hred[2];
    __shared__ int sh_pos, sh_atom;
    __shared__ float sh_amp;
    int pos, atom; float amp;
    if (s == NSTEP - 1) {
        const float4* l2r = l2 + ((NSTEP - 1) & 1) * (BATCH * NATOM);
        float ba = -1.f, bsg = 0.f, bi = 3.0e7f;
        const float4 e0 = l2r[(b << 8) + o];
        const float4 e1 = l2r[(b << 8) + 128 + o];
        cmax(ba, bsg, bi, e0.x, e0.y, e0.z);
        cmax(ba, bsg, bi, e1.x, e1.y, e1.z);
#pragma unroll
        for (int m = 32; m >= 1; m >>= 1) {
            const float oa = __shfl_xor(ba, m);
            const float os = __shfl_xor(bsg, m);
            const float oi = __shfl_xor(bi, m);
            cmax(ba, bsg, bi, oa, os, oi);
        }
        if ((o & 63) == 0) hred[o >> 6] = make_float4(ba, bsg, bi, 0.f);
        __syncthreads();
        if (o == 0) {
            float4 r = hred[0];
            const float4 q = hred[1];
            if (q.x > r.x || (q.x == r.x && q.z < r.z)) r = q;
            const int idx = (int)r.z;
            sh_atom = idx / TOUT;
            sh_pos = idx - sh_atom * TOUT;
            sh_amp = r.y;
        }
        __syncthreads();
        pos = sh_pos; atom = sh_atom; amp = sh_amp;
    } else {
        pos  = pos_a[s * BATCH + b];
        atom = atom_a[s * BATCH + b];
        amp  = amp_a[s * BATCH + b];
    }
    const float posn = (float)pos / 32513.0f;
    float sum = br[o];
    for (int c = 0; c < 128; ++c) {
        const float pa = wpa[c * 2] * posn + wpa[c * 2 + 1] * amp + bpa[c];
        const float at = wat[c * 256 + atom] + bat[c];
        sum += wr[o * 256 + c] * pa + wr[o * 256 + 128 + c] * at;
    }
    out[(b * 128 + o) * NSTEP + s] = sum;
}

extern "C" void kernel_launch(void* const* d_in, const int* in_sizes, int n_in,
                              void* d_out, int out_size, void* d_ws, size_t ws_size,
                              hipStream_t stream) {
    const float* x   = (const float*)d_in[0];
    const float* d   = (const float*)d_in[1];
    const float* wpa = (const float*)d_in[2];
    const float* bpa = (const float*)d_in[3];
    const float* wat = (const float*)d_in[4];
    const float* bat = (const float*)d_in[5];
    const float* wr  = (const float*)d_in[6];
    const float* br  = (const float*)d_in[7];
    float* out = (float*)d_out;

    char* ws = (char*)d_ws;
    float2* bm     = (float2*)ws;                                   // 4,177,920
    float4* l2     = (float4*)(ws + 4177920);                       // 65,536
    int*    pos_a  = (int*)(ws + 4243456);                          // 512
    int*    atom_a = (int*)(ws + 4243968);                          // 512
    float*  amp_a  = (float*)(ws + 4244480);                        // 512
    uint4*  dhF    = (uint4*)(ws + 4244992);                        // 131,072
    uint4*  dlF    = (uint4*)(ws + 4376064);                        // 131,072
    // union region @4507136: xhl4 (4,227,072) dead after k_init; resid0/1 after
    uint4*  xhl4   = (uint4*)(ws + 4507136);
    float*  resid0 = (float*)(ws + 4507136);                        // 1,048,576
    float*  resid1 = (float*)(ws + 5555712);                        // 1,048,576

    const int prep_n = BATCH * XSTR + NATOM * 32;
    k_prep<<<(prep_n + 255) / 256, 256, 0, stream>>>(x, d, xhl4, dhF, dlF);
    k_init<<<dim3(128, 4, 8), 256, 0, stream>>>(xhl4, dhF, dlF, bm);
    k_lvl2<<<dim3(32, 8), 256, 0, stream>>>(bm, l2);
    // xhl4 dead from here; resid buffers reuse its space (stream-ordered)
    hipMemcpyAsync(resid0, x, (size_t)BATCH * NS * sizeof(float),
                   hipMemcpyDeviceToDevice, stream);
    for (int st = 0; st < NSTEP - 1; ++st) {
        float* rs = (st & 1) ? resid1 : resid0;
        float* rd = (st & 1) ? resid0 : resid1;
        k_step<<<dim3(32, 8), 512, 0, stream>>>(d, rs, rd, bm, l2,
                                                pos_a, atom_a, amp_a, st);
    }
    k_head<<<dim3(16, 8), 128, 0, stream>>>(pos_a, atom_a, amp_a, l2,
                                            wpa, bpa, wat, bat, wr, br, out);
}

// Round 11
// 406.235 us; speedup vs baseline: 1.2551x; 1.0040x over previous
//
#include <hip/hip_runtime.h>
#include <hip/hip_bf16.h>
#include <float.h>

#define NS 32768
#define KER 256
#define TOUT 32513
#define NATOM 256
#define NSTEP 16
#define BATCH 8
#define NBLK 255
#define XSTR 33024   // NS + 256 pad (zero-filled)
#define SW4(i) ((i) + (((i) >> 5) << 2))

typedef __attribute__((ext_vector_type(8))) _Float16 half8;
typedef __attribute__((ext_vector_type(16))) float f32x16;
typedef __attribute__((ext_vector_type(4))) unsigned int uint4v;

__device__ __forceinline__ void cmax(float& ba, float& bs, float& bi,
                                     float oa, float os, float oi) {
    if (oa > ba || (oa == ba && oi < bi)) { ba = oa; bs = os; bi = oi; }
}

__device__ __forceinline__ void fma8(float acc[8], float4 dA, float4 dB,
                                     float4 w0, float4 w1, float4 w2, float4 w3) {
    float w[16] = {w0.x,w0.y,w0.z,w0.w, w1.x,w1.y,w1.z,w1.w,
                   w2.x,w2.y,w2.z,w2.w, w3.x,w3.y,w3.z,w3.w};
    float dv[8] = {dA.x,dA.y,dA.z,dA.w, dB.x,dB.y,dB.z,dB.w};
#pragma unroll
    for (int i = 0; i < 8; ++i)
#pragma unroll
        for (int j = 0; j < 8; ++j)
            acc[j] = fmaf(dv[i], w[i + j], acc[j]);
}

__device__ __forceinline__ unsigned short f16hi(float v) {
    return __builtin_bit_cast(unsigned short, (_Float16)v);
}
__device__ __forceinline__ unsigned short f16lo(float v) {
    const _Float16 h = (_Float16)v;
    return __builtin_bit_cast(unsigned short, (_Float16)(v - (float)h));
}

// xhl4[i] = {hi01, hi23, lo01, lo23} f16 of x[i..i+3] (redundant quads, one
// b128 read covers hi+lo of 4 elems). dhF/dlF fragment-major.
__global__ __launch_bounds__(256) void k_prep(const float* __restrict__ x,
                                              const float* __restrict__ d,
                                              uint4* __restrict__ xhl4,
                                              uint4* __restrict__ dhF,
                                              uint4* __restrict__ dlF) {
    const int gid = blockIdx.x * 256 + threadIdx.x;
    const int NXE = BATCH * XSTR;
    if (gid < NXE) {
        const int b = gid / XSTR, i = gid - b * XSTR;
        float v[4];
#pragma unroll
        for (int u = 0; u < 4; ++u)
            v[u] = (i + u < NS) ? x[b * NS + i + u] : 0.f;
        uint4 q;
        q.x = (unsigned int)f16hi(v[0]) | ((unsigned int)f16hi(v[1]) << 16);
        q.y = (unsigned int)f16hi(v[2]) | ((unsigned int)f16hi(v[3]) << 16);
        q.z = (unsigned int)f16lo(v[0]) | ((unsigned int)f16lo(v[1]) << 16);
        q.w = (unsigned int)f16lo(v[2]) | ((unsigned int)f16lo(v[3]) << 16);
        xhl4[gid] = q;
    } else {
        const int j = gid - NXE;
        if (j < NATOM * 32) {
            const int kg = j >> 8, atom = j & 255;
            const float* dp = d + atom * 256 + (kg << 3);
            uint4 hw, lw;
            hw.x = (unsigned int)f16hi(dp[0]) | ((unsigned int)f16hi(dp[1]) << 16);
            hw.y = (unsigned int)f16hi(dp[2]) | ((unsigned int)f16hi(dp[3]) << 16);
            hw.z = (unsigned int)f16hi(dp[4]) | ((unsigned int)f16hi(dp[5]) << 16);
            hw.w = (unsigned int)f16hi(dp[6]) | ((unsigned int)f16hi(dp[7]) << 16);
            lw.x = (unsigned int)f16lo(dp[0]) | ((unsigned int)f16lo(dp[1]) << 16);
            lw.y = (unsigned int)f16lo(dp[2]) | ((unsigned int)f16lo(dp[3]) << 16);
            lw.z = (unsigned int)f16lo(dp[4]) | ((unsigned int)f16lo(dp[5]) << 16);
            lw.w = (unsigned int)f16lo(dp[6]) | ((unsigned int)f16lo(dp[7]) << 16);
            dhF[(kg << 8) + atom] = hw;
            dlF[(kg << 8) + atom] = lw;
        }
    }
}

// 32x32x16_f16 MFMA correlation, 2m x 2n tile, diagonal-B register FIFO
// (Toeplitz: B(nt=1,kk) == B(nt=0,kk+2) -> 2 LDS b128/kk instead of 4).
// grid (128 t-chunks of 256, 4 atom-groups of 64, 8 b), block 256 (4 waves).
// Epilogue: u64 argmax keys (abs || ~idx || sign) -> 1-value shuffle ladder.
__global__ __launch_bounds__(256) void k_init(const uint4* __restrict__ xhl4,
                                              const uint4* __restrict__ dhF,
                                              const uint4* __restrict__ dlF,
                                              float2* __restrict__ bm) {
    const int c = blockIdx.x, mg = blockIdx.y, b = blockIdx.z;
    const int tid = threadIdx.x;
    const int w = tid >> 6, l = tid & 63;
    const int n = l & 31, h = l >> 5;
    __shared__ uint4 xw[512];                 // 256-t window + 252 tail
    __shared__ unsigned long long wmax[4][64];
    const int t0 = c << 8;
    xw[tid] = xhl4[b * XSTR + t0 + tid];
    xw[tid + 256] = xhl4[b * XSTR + t0 + 256 + tid];
    __syncthreads();

    f32x16 acc00, acc01, acc10, acc11;
#pragma unroll
    for (int j = 0; j < 16; ++j) { acc00[j] = 0.f; acc01[j] = 0.f;
                                   acc10[j] = 0.f; acc11[j] = 0.f; }

    const int abase = (mg << 6) + n;
    const int sbb = (w << 6) + n + (h << 3);

    // B fragment FIFO: slot kk&3 holds F(kk); live window [kk, kk+2].
    half8 fbh[4], fbl[4];
    {
        const uint4 q0 = xw[sbb], q1 = xw[sbb + 4];
        const uint4v hv = {q0.x, q0.y, q1.x, q1.y};
        const uint4v lv = {q0.z, q0.w, q1.z, q1.w};
        fbh[0] = __builtin_bit_cast(half8, hv);
        fbl[0] = __builtin_bit_cast(half8, lv);
    }
    {
        const uint4 q0 = xw[sbb + 16], q1 = xw[sbb + 20];
        const uint4v hv = {q0.x, q0.y, q1.x, q1.y};
        const uint4v lv = {q0.z, q0.w, q1.z, q1.w};
        fbh[1] = __builtin_bit_cast(half8, hv);
        fbl[1] = __builtin_bit_cast(half8, lv);
    }

#pragma unroll 4
    for (int kk = 0; kk < 16; ++kk) {
        const int kg = (kk << 1) + h;
        const half8 ah0 = __builtin_bit_cast(half8, dhF[(kg << 8) + abase]);
        const half8 al0 = __builtin_bit_cast(half8, dlF[(kg << 8) + abase]);
        const half8 ah1 = __builtin_bit_cast(half8, dhF[(kg << 8) + abase + 32]);
        const half8 al1 = __builtin_bit_cast(half8, dlF[(kg << 8) + abase + 32]);
        {   // load F(kk+2) into slot (kk+2)&3  (also the nt=1 fragment this iter)
            const int sN = sbb + ((kk + 2) << 4);
            const uint4 q0 = xw[sN], q1 = xw[sN + 4];
            const uint4v hv = {q0.x, q0.y, q1.x, q1.y};
            const uint4v lv = {q0.z, q0.w, q1.z, q1.w};
            fbh[(kk + 2) & 3] = __builtin_bit_cast(half8, hv);
            fbl[(kk + 2) & 3] = __builtin_bit_cast(half8, lv);
        }
        const half8 b0h = fbh[kk & 3],       b0l = fbl[kk & 3];
        const half8 b1h = fbh[(kk + 2) & 3], b1l = fbl[(kk + 2) & 3];
        acc00 = __builtin_amdgcn_mfma_f32_32x32x16_f16(ah0, b0l, acc00, 0, 0, 0);
        acc00 = __builtin_amdgcn_mfma_f32_32x32x16_f16(al0, b0h, acc00, 0, 0, 0);
        acc00 = __builtin_amdgcn_mfma_f32_32x32x16_f16(ah0, b0h, acc00, 0, 0, 0);
        acc10 = __builtin_amdgcn_mfma_f32_32x32x16_f16(ah1, b0l, acc10, 0, 0, 0);
        acc10 = __builtin_amdgcn_mfma_f32_32x32x16_f16(al1, b0h, acc10, 0, 0, 0);
        acc10 = __builtin_amdgcn_mfma_f32_32x32x16_f16(ah1, b0h, acc10, 0, 0, 0);
        acc01 = __builtin_amdgcn_mfma_f32_32x32x16_f16(ah0, b1l, acc01, 0, 0, 0);
        acc01 = __builtin_amdgcn_mfma_f32_32x32x16_f16(al0, b1h, acc01, 0, 0, 0);
        acc01 = __builtin_amdgcn_mfma_f32_32x32x16_f16(ah0, b1h, acc01, 0, 0, 0);
        acc11 = __builtin_amdgcn_mfma_f32_32x32x16_f16(ah1, b1l, acc11, 0, 0, 0);
        acc11 = __builtin_amdgcn_mfma_f32_32x32x16_f16(al1, b1h, acc11, 0, 0, 0);
        acc11 = __builtin_amdgcn_mfma_f32_32x32x16_f16(ah1, b1h, acc11, 0, 0, 0);
    }

    // Epilogue: C col=lane&31 (t), row=(r&3)+8*(r>>2)+4*h (atom within 32).
    // u64 key = abs_bits<<32 | (0x7FFFFF-idx)<<1 | signbit  (max => argmax,
    // tie -> lowest idx, matching cmax semantics exactly).
    const int tb = t0 + (w << 6) + n;
#pragma unroll
    for (int mt = 0; mt < 2; ++mt) {
#pragma unroll
        for (int r = 0; r < 16; ++r) {
            const int amt = (mt << 5) + (r & 3) + ((r >> 2) << 3) + (h << 2);
            const int idx0 = ((mg << 6) + amt) * TOUT + tb;
            const float v0 = (mt == 0) ? acc00[r] : acc10[r];
            const float v1 = (mt == 0) ? acc01[r] : acc11[r];
            const unsigned int c0 = (0x7FFFFFu - (unsigned int)idx0);
            unsigned long long k0 = 0ull, k1 = 0ull;
            if (tb < TOUT)
                k0 = ((unsigned long long)__float_as_uint(fabsf(v0)) << 32)
                   | ((unsigned long long)(c0 << 1))
                   | (unsigned long long)(__float_as_uint(v0) >> 31);
            if (tb + 32 < TOUT)
                k1 = ((unsigned long long)__float_as_uint(fabsf(v1)) << 32)
                   | ((unsigned long long)((c0 - 32u) << 1))
                   | (unsigned long long)(__float_as_uint(v1) >> 31);
            unsigned long long k = (k1 > k0) ? k1 : k0;
#pragma unroll
            for (int m = 1; m <= 16; m <<= 1) {
                const unsigned long long ok = __shfl_xor(k, m, 32);
                if (ok > k) k = ok;
            }
            if (n == 0) wmax[w][amt] = k;
        }
    }
    __syncthreads();
    if (tid < 128) {
        const int a = tid & 63, p = tid >> 6;
        unsigned long long k = wmax[(p << 1)][a];
        const unsigned long long k2 = wmax[(p << 1) + 1][a];
        if (k2 > k) k = k2;
        const int blk = (c << 1) + p;
        if (blk < NBLK) {
            const float av = __uint_as_float((unsigned int)(k >> 32));
            const unsigned int lo = (unsigned int)k;
            const int idx = 0x7FFFFF - (int)((lo >> 1) & 0x7FFFFFu);
            const float bsg = (lo & 1u) ? -av : av;
            bm[(size_t)((b << 8) + (mg << 6) + a) * NBLK + blk] =
                make_float2(bsg, (float)idx);
        }
    }
}

// Per-atom (level-2) maxima over all blocks -> l2 buffer 0.
__global__ __launch_bounds__(256) void k_lvl2(const float2* __restrict__ bm,
                                              float4* __restrict__ l2) {
    const int b = blockIdx.y;
    const int oglob = blockIdx.x * 8 + (threadIdx.x >> 5);
    const int lane = threadIdx.x & 31;
    const float2* row = bm + (size_t)(b * NATOM + oglob) * NBLK;
    float ba = -1.f, bsg = 0.f, bi = 3.0e7f;
    for (int i = lane; i < NBLK; i += 32) {
        const float2 e = row[i];
        cmax(ba, bsg, bi, fabsf(e.x), e.x, e.y);
    }
#pragma unroll
    for (int m = 16; m >= 1; m >>= 1) {
        const float oa = __shfl_xor(ba, m, 32);
        const float os = __shfl_xor(bsg, m, 32);
        const float oi = __shfl_xor(bi, m, 32);
        cmax(ba, bsg, bi, oa, os, oi);
    }
    if (lane == 0) l2[(b << 8) + oglob] = make_float4(ba, bsg, bi, 0.f);
}

// One MP step. New vs r10 (bitwise-identical results):
//  - windowed copy-forward for steps>=2 (dst is 2-stale: only
//    window(pos[step-1]) U window(pos[step]) can differ; og==0 writes those
//    <=512 samples; steps 0/1 do the full-slice copy; step 0 src = x).
//  - incremental l2 refresh: full 255-entry rescan only when the atom's old
//    argmax block lies in [bs0,be0]; else combine old entry with upd[] (same
//    strict total order -> same winner).
__global__ __launch_bounds__(512) void k_step(const float* __restrict__ d,
                                              const float* __restrict__ resid_src,
                                              float* __restrict__ resid_dst,
                                              float2* __restrict__ bm,
                                              float4* __restrict__ l2,
                                              int* __restrict__ pos_a,
                                              int* __restrict__ atom_a,
                                              float* __restrict__ amp_a,
                                              int step) {
    const int og = blockIdx.x, b = blockIdx.y;
    const int tid = threadIdx.x;
    const int wave = tid >> 6, lane = tid & 63;
    __shared__ float dt[2048];
    __shared__ float rsu[1024];
    __shared__ float4 sred[8];
    __shared__ float4 upd[8][5];
    __shared__ int sh_pos, sh_atom, sh_prev;
    __shared__ float sh_amp;

    ((float4*)dt)[tid] = ((const float4*)(d + og * 2048))[tid];
    if (tid == 0 && step >= 2) sh_prev = pos_a[(step - 1) * BATCH + b];
    const float4* l2r = l2 + (step & 1) * (BATCH * NATOM);
    float4*       l2w = l2 + ((step + 1) & 1) * (BATCH * NATOM);

    {
        float ba = -1.f, bsg = 0.f, bi = 3.0e7f;
        if (tid < 256) {
            const float4 e = l2r[(b << 8) + tid];
            ba = e.x; bsg = e.y; bi = e.z;
        }
#pragma unroll
        for (int m = 32; m >= 1; m >>= 1) {
            const float oa = __shfl_xor(ba, m);
            const float os = __shfl_xor(bsg, m);
            const float oi = __shfl_xor(bi, m);
            cmax(ba, bsg, bi, oa, os, oi);
        }
        if (lane == 0) sred[wave] = make_float4(ba, bsg, bi, 0.f);
    }
    __syncthreads();
    if (tid == 0) {
        float4 r = sred[0];
#pragma unroll
        for (int i = 1; i < 8; ++i) {
            const float4 q = sred[i];
            if (q.x > r.x || (q.x == r.x && q.z < r.z)) r = q;
        }
        const int idx = (int)r.z;
        const int atom = idx / TOUT;
        const int pos = idx - atom * TOUT;
        sh_pos = pos; sh_atom = atom; sh_amp = r.y;
        if (og == 0) {
            pos_a[step * BATCH + b] = pos;
            atom_a[step * BATCH + b] = atom;
            amp_a[step * BATCH + b] = r.y;
        }
    }
    __syncthreads();
    const int p = sh_pos, atom_s = sh_atom;
    const float amp = sh_amp;

    // ---- copy-forward dst := r_{step+1} ----
    if (step < 2) {
        for (int i = tid; i < 1024; i += 512) {
            const int g = (og << 10) + i;
            float v = resid_src[(size_t)b * NS + g];
            const int off = g - p;
            if (off >= 0 && off < KER)
                v = __fsub_rn(v, __fmul_rn(amp, d[atom_s * KER + off]));
            resid_dst[(size_t)b * NS + g] = v;
        }
    } else if (og == 0) {
        if (tid < 256) {
            const int g = p + tid;   // cur window: subtract (g <= NS-1 always)
            resid_dst[(size_t)b * NS + g] =
                __fsub_rn(resid_src[(size_t)b * NS + g],
                          __fmul_rn(amp, d[atom_s * KER + tid]));
        } else {
            const int g = sh_prev + (tid - 256);  // prev window \ cur: pure copy
            if (g < p || g > p + 255)
                resid_dst[(size_t)b * NS + g] = resid_src[(size_t)b * NS + g];
        }
    }

    // ---- residual window for the bm update (r_{step+1}, exact order) ----
    int tlo = p - 255; if (tlo < 0) tlo = 0;
    int thi = p + 255; if (thi > TOUT - 1) thi = TOUT - 1;
    const int bs0 = tlo >> 7, be0 = thi >> 7;
    const int rbase = bs0 << 7;
    const int nblks = be0 - bs0 + 1;
    const int rlen = (nblks << 7) + 255;
    for (int i = tid; i < rlen; i += 512) {
        const int g = rbase + i;
        float v = (g < NS) ? resid_src[(size_t)b * NS + g] : 0.f;
        const int off = g - p;
        if (g < NS && off >= 0 && off < KER)
            v = __fsub_rn(v, __fmul_rn(amp, d[atom_s * KER + off]));
        rsu[SW4(i)] = v;
    }
    __syncthreads();

    const int lg = lane >> 4, l16 = lane & 15;
    const float* dp = dt + (wave << 8) + (lg << 6);
    const int atomg = (og << 3) + wave;
    for (int bb = 0; bb < nblks; ++bb) {
        const int blk = bs0 + bb;
        const int t0r = (bb << 7) + (l16 << 3) + (lg << 6);
        float acc[8];
#pragma unroll
        for (int j = 0; j < 8; ++j) acc[j] = 0.f;
        float4 A0 = *(const float4*)(rsu + SW4(t0r));
        float4 A1 = *(const float4*)(rsu + SW4(t0r + 4));
        float4 B0 = *(const float4*)(rsu + SW4(t0r + 8));
        float4 B1 = *(const float4*)(rsu + SW4(t0r + 12));
#pragma unroll
        for (int kk = 0; kk < 64; kk += 16) {
            const float4 d0 = *(const float4*)(dp + kk);
            const float4 d1 = *(const float4*)(dp + kk + 4);
            const float4 N0 = *(const float4*)(rsu + SW4(t0r + kk + 16));
            const float4 N1 = *(const float4*)(rsu + SW4(t0r + kk + 20));
            fma8(acc, d0, d1, A0, A1, B0, B1);
            const float4 d2 = *(const float4*)(dp + kk + 8);
            const float4 d3 = *(const float4*)(dp + kk + 12);
            const float4 M0 = *(const float4*)(rsu + SW4(t0r + kk + 24));
            const float4 M1 = *(const float4*)(rsu + SW4(t0r + kk + 28));
            fma8(acc, d2, d3, B0, B1, N0, N1);
            A0 = N0; A1 = N1; B0 = M0; B1 = M1;
        }
#pragma unroll
        for (int j = 0; j < 8; ++j) {
            acc[j] += __shfl_xor(acc[j], 16);
            acc[j] += __shfl_xor(acc[j], 32);
        }
        float ba = -1.f, bsg = 0.f, bi = 3.0e7f;
        const int tbp = rbase + (bb << 7) + (l16 << 3);
#pragma unroll
        for (int j = 0; j < 8; ++j) {
            const int t = tbp + j;
            const float av = fabsf(acc[j]);
            if (t < TOUT && av > ba) { ba = av; bsg = acc[j]; bi = (float)(atomg * TOUT + t); }
        }
#pragma unroll
        for (int m = 32; m >= 1; m >>= 1) {
            const float oa = __shfl_xor(ba, m);
            const float os = __shfl_xor(bsg, m);
            const float oi = __shfl_xor(bi, m);
            cmax(ba, bsg, bi, oa, os, oi);
        }
        if (lane == 0) {
            bm[(size_t)(b * NATOM + atomg) * NBLK + blk] = make_float2(bsg, bi);
            upd[wave][bb] = make_float4(ba, bsg, bi, 0.f);
        }
    }
    __syncthreads();

    // ---- l2 refresh: rescan only if old winner's block was updated ----
    {
        const float4 eo = l2r[(b << 8) + atomg];          // broadcast load
        const int oblk = ((int)eo.z - atomg * TOUT) >> 7; // exact (idx < 2^23)
        if (oblk >= bs0 && oblk <= be0) {
            float ba = -1.f, bsg = 0.f, bi = 3.0e7f;
            const float2* row = bm + (size_t)(b * NATOM + atomg) * NBLK;
            for (int i = lane; i < NBLK; i += 64) {
                if (i >= bs0 && i <= be0) {
                    const float4 e2 = upd[wave][i - bs0];
                    cmax(ba, bsg, bi, e2.x, e2.y, e2.z);
                } else {
                    const float2 e2 = row[i];
                    cmax(ba, bsg, bi, fabsf(e2.x), e2.x, e2.y);
                }
            }
#pragma unroll
            for (int m = 32; m >= 1; m >>= 1) {
                const float oa = __shfl_xor(ba, m);
                const float os = __shfl_xor(bsg, m);
                const float oi = __shfl_xor(bi, m);
                cmax(ba, bsg, bi, oa, os, oi);
            }
            if (lane == 0) l2w[(b << 8) + atomg] = make_float4(ba, bsg, bi, 0.f);
        } else if (lane == 0) {
            float ba = eo.x, bsg = eo.y, bi = eo.z;
            for (int bb = 0; bb < nblks; ++bb) {
                const float4 e2 = upd[wave][bb];
                cmax(ba, bsg, bi, e2.x, e2.y, e2.z);
            }
            l2w[(b << 8) + atomg] = make_float4(ba, bsg, bi, 0.f);
        }
    }
}

// Head; blocks with s==15 compute the final select inline from l2 parity buf.
__global__ __launch_bounds__(128) void k_head(const int* __restrict__ pos_a,
                                              const int* __restrict__ atom_a,
                                              const float* __restrict__ amp_a,
                                              const float4* __restrict__ l2,
                                              const float* __restrict__ wpa,
                                              const float* __restrict__ bpa,
                                              const float* __restrict__ wat,
                                              const float* __restrict__ bat,
                                              const float* __restrict__ wr,
                                              const float* __restrict__ br,
                                              float* __restrict__ out) {
    const int s = blockIdx.x, b = blockIdx.y;
    const int o = threadIdx.x;
    __shared__ float4 hred[2];
    __shared__ int sh_pos, sh_atom;
    __shared__ float sh_amp;
    int pos, atom; float amp;
    if (s == NSTEP - 1) {
        const float4* l2r = l2 + ((NSTEP - 1) & 1) * (BATCH * NATOM);
        float ba = -1.f, bsg = 0.f, bi = 3.0e7f;
        const float4 e0 = l2r[(b << 8) + o];
        const float4 e1 = l2r[(b << 8) + 128 + o];
        cmax(ba, bsg, bi, e0.x, e0.y, e0.z);
        cmax(ba, bsg, bi, e1.x, e1.y, e1.z);
#pragma unroll
        for (int m = 32; m >= 1; m >>= 1) {
            const float oa = __shfl_xor(ba, m);
            const float os = __shfl_xor(bsg, m);
            const float oi = __shfl_xor(bi, m);
            cmax(ba, bsg, bi, oa, os, oi);
        }
        if ((o & 63) == 0) hred[o >> 6] = make_float4(ba, bsg, bi, 0.f);
        __syncthreads();
        if (o == 0) {
            float4 r = hred[0];
            const float4 q = hred[1];
            if (q.x > r.x || (q.x == r.x && q.z < r.z)) r = q;
            const int idx = (int)r.z;
            sh_atom = idx / TOUT;
            sh_pos = idx - sh_atom * TOUT;
            sh_amp = r.y;
        }
        __syncthreads();
        pos = sh_pos; atom = sh_atom; amp = sh_amp;
    } else {
        pos  = pos_a[s * BATCH + b];
        atom = atom_a[s * BATCH + b];
        amp  = amp_a[s * BATCH + b];
    }
    const float posn = (float)pos / 32513.0f;
    float sum = br[o];
    for (int c = 0; c < 128; ++c) {
        const float pa = wpa[c * 2] * posn + wpa[c * 2 + 1] * amp + bpa[c];
        const float at = wat[c * 256 + atom] + bat[c];
        sum += wr[o * 256 + c] * pa + wr[o * 256 + 128 + c] * at;
    }
    out[(b * 128 + o) * NSTEP + s] = sum;
}

extern "C" void kernel_launch(void* const* d_in, const int* in_sizes, int n_in,
                              void* d_out, int out_size, void* d_ws, size_t ws_size,
                              hipStream_t stream) {
    const float* x   = (const float*)d_in[0];
    const float* d   = (const float*)d_in[1];
    const float* wpa = (const float*)d_in[2];
    const float* bpa = (const float*)d_in[3];
    const float* wat = (const float*)d_in[4];
    const float* bat = (const float*)d_in[5];
    const float* wr  = (const float*)d_in[6];
    const float* br  = (const float*)d_in[7];
    float* out = (float*)d_out;

    char* ws = (char*)d_ws;
    float2* bm     = (float2*)ws;                                   // 4,177,920
    float4* l2     = (float4*)(ws + 4177920);                       // 65,536
    int*    pos_a  = (int*)(ws + 4243456);                          // 512
    int*    atom_a = (int*)(ws + 4243968);                          // 512
    float*  amp_a  = (float*)(ws + 4244480);                        // 512
    uint4*  dhF    = (uint4*)(ws + 4244992);                        // 131,072
    uint4*  dlF    = (uint4*)(ws + 4376064);                        // 131,072
    // union region @4507136: xhl4 (4,227,072) dead after k_init; resid0/1 after
    uint4*  xhl4   = (uint4*)(ws + 4507136);
    float*  resid0 = (float*)(ws + 4507136);                        // 1,048,576
    float*  resid1 = (float*)(ws + 5555712);                        // 1,048,576

    const int prep_n = BATCH * XSTR + NATOM * 32;
    k_prep<<<(prep_n + 255) / 256, 256, 0, stream>>>(x, d, xhl4, dhF, dlF);
    k_init<<<dim3(128, 4, 8), 256, 0, stream>>>(xhl4, dhF, dlF, bm);
    k_lvl2<<<dim3(32, 8), 256, 0, stream>>>(bm, l2);
    // xhl4 dead from here; resid buffers reuse its space (stream-ordered).
    // Step 0 reads x directly (r_0 = x); steps 0/1 fully populate dst buffers,
    // steps >=2 write only the two changed 256-sample windows.
    for (int st = 0; st < NSTEP - 1; ++st) {
        const float* rs = (st == 0) ? x : ((st & 1) ? resid1 : resid0);
        float* rd = (st & 1) ? resid0 : resid1;
        k_step<<<dim3(32, 8), 512, 0, stream>>>(d, rs, rd, bm, l2,
                                                pos_a, atom_a, amp_a, st);
    }
    k_head<<<dim3(16, 8), 128, 0, stream>>>(pos_a, atom_a, amp_a, l2,
                                            wpa, bpa, wat, bat, wr, br, out);
}